// Round 12
// baseline (164.284 us; speedup 1.0000x reference)
//
#include <hip/hip_runtime.h>

#define TPB 256

// Gaussian kernel, sigma=1.1, ksize=5 (precomputed, normalized)
#define K0 0.0707663f
#define K1 0.2444606f
#define K2 0.3695462f

// gradmag f4-unit block counts per scale (B=2): units = 2*N*N*(N/4)
#define EB0 8000
#define EB1 1000
#define EB2 125
// energy z8-pair block counts: units = 2*N*N*(N/8)
#define PB0 4000
#define PB1 500
#define PB2 63      // 16128 threads, guard idx<16000
// blur y4-units per scale
#define BB0 2000
#define BB1 250
#define BB2 32      // guard idx<8000
// resize
#define RBLK 6000

typedef float f4 __attribute__((ext_vector_type(4)));

__device__ __forceinline__ f4 ld4(const float* __restrict__ p) { return *(const f4*)p; }

__device__ __forceinline__ int rref(int i, int n) {
    return i < 0 ? -i : (i >= n ? 2 * n - 2 - i : i);
}

// -------- resize 160->80, f4 over z. ratio = 159/79 = 2 + 1/79 -> i0 = 2i exactly --------
__device__ __forceinline__ void resize80_f4(const float* __restrict__ in,
                                            float* __restrict__ out, long idx) {
    int z4 = (int)(idx % 20); long r = idx / 20;
    int y = (int)(r % 80); r /= 80;
    int x = (int)(r % 80); int bc = (int)(r / 80);
    int z = z4 * 4;

    const float RT = 159.f / 79.f;
    float wx = (float)x * RT - (float)(2 * x);
    float wy = (float)y * RT - (float)(2 * y);
    const float* p = in + (long)bc * 4096000L + (long)(2 * x) * 25600 + (long)(2 * y) * 160 + 2 * z;
    f4 a00 = ld4(p),         a01 = ld4(p + 4);
    f4 b00 = ld4(p + 160),   b01 = ld4(p + 164);
    f4 c00 = ld4(p + 25600), c01 = ld4(p + 25604);
    f4 d00 = ld4(p + 25760), d01 = ld4(p + 25764);

    f4 outv;
#pragma unroll
    for (int j = 0; j < 4; ++j) {
        int zo = z + j;
        float wz = (float)zo * RT - (float)(2 * zo);
        float e0, e1, f0, f1, g0, g1, h0, h1;
        if (j < 2) {
            e0 = a00[2 * j]; e1 = a00[2 * j + 1]; f0 = b00[2 * j]; f1 = b00[2 * j + 1];
            g0 = c00[2 * j]; g1 = c00[2 * j + 1]; h0 = d00[2 * j]; h1 = d00[2 * j + 1];
        } else {
            e0 = a01[2 * j - 4]; e1 = a01[2 * j - 3]; f0 = b01[2 * j - 4]; f1 = b01[2 * j - 3];
            g0 = c01[2 * j - 4]; g1 = c01[2 * j - 3]; h0 = d01[2 * j - 4]; h1 = d01[2 * j - 3];
        }
        float za = e0 + wz * (e1 - e0);
        float zb = f0 + wz * (f1 - f0);
        float zc = g0 + wz * (g1 - g0);
        float zd = h0 + wz * (h1 - h0);
        float cy0 = za + wy * (zb - za);
        float cy1 = zc + wy * (zd - zc);
        outv[j] = cy0 + wx * (cy1 - cy0);
    }
    *(f4*)(out + (long)bc * 512000L + (long)x * 6400 + (long)y * 80 + z) = outv;
}

// -------- scalar trilinear resize (M=40), align_corners --------
template <int NIN, int M>
__device__ __forceinline__ void resize_one(const float* __restrict__ in,
                                           float* __restrict__ out, long idx) {
    constexpr float ratio = (float)((NIN - 1.0) / (M - 1.0));
    int z = (int)(idx % M); long r = idx / M;
    int y = (int)(r % M);   r /= M;
    int x = (int)(r % M);   int bc = (int)(r / M);

    float cx = (float)x * ratio, cy = (float)y * ratio, cz = (float)z * ratio;
    int x0 = min((int)cx, NIN - 1), y0 = min((int)cy, NIN - 1), z0 = min((int)cz, NIN - 1);
    float wx = cx - (float)x0, wy = cy - (float)y0, wz = cz - (float)z0;
    int x1 = min(x0 + 1, NIN - 1), y1 = min(y0 + 1, NIN - 1), z1 = min(z0 + 1, NIN - 1);

    const float* p = in + (long)bc * NIN * NIN * NIN;
    constexpr long sx = (long)NIN * NIN;
#define AT(xi, yi, zi) p[(long)(xi) * sx + (long)(yi) * NIN + (zi)]
    float c00 = AT(x0, y0, z0) * (1.f - wz) + AT(x0, y0, z1) * wz;
    float c01 = AT(x0, y1, z0) * (1.f - wz) + AT(x0, y1, z1) * wz;
    float c10 = AT(x1, y0, z0) * (1.f - wz) + AT(x1, y0, z1) * wz;
    float c11 = AT(x1, y1, z0) * (1.f - wz) + AT(x1, y1, z1) * wz;
#undef AT
    float c0 = c00 * (1.f - wy) + c01 * wy;
    float c1 = c10 * (1.f - wy) + c11 * wy;
    out[idx] = c0 * (1.f - wx) + c1 * wx;
}

__global__ __launch_bounds__(TPB)
void resize_all_kernel(const float* __restrict__ D, const float* __restrict__ I,
                       float* __restrict__ ds1, float* __restrict__ ds2,
                       float* __restrict__ is1, float* __restrict__ is2) {
    long idx = (long)blockIdx.x * TPB + threadIdx.x;
    if (idx < 768000L) { resize80_f4(D, ds1, idx); return; }
    idx -= 768000L;
    if (idx < 256000L) { resize80_f4(I, is1, idx); return; }
    idx -= 256000L;
    if (idx < 384000L) { resize_one<160, 40>(D, ds2, idx); return; }
    idx -= 384000L;
    resize_one<160, 40>(I, is2, idx);
}

// -------- gradient magnitude, f4 over z --------
template <int N>
__device__ __forceinline__ void gradmag_one(const float* __restrict__ img,
                                            float* __restrict__ g, long idx) {
    constexpr int NZ4 = N / 4;
    constexpr long n2 = (long)N * N, n3 = n2 * N;
    int z4 = (int)(idx % NZ4); long r = idx / NZ4;
    int y = (int)(r % N); r /= N;
    int x = (int)(r % N); int b = (int)(r / N);
    int z = z4 * 4;

    const float* base = img + (long)b * n3;
    const float* rowc = base + (long)x * n2 + (long)y * N;
    f4 cur = ld4(rowc + z);
    f4 prev = (z > 0) ? ld4(rowc + z - 4) : cur;
    f4 next = (z + 4 < N) ? ld4(rowc + z + 4) : cur;

    int xm = max(x - 1, 0), xp = min(x + 1, N - 1);
    int ym = max(y - 1, 0), yp = min(y + 1, N - 1);
    float hx = (x == 0 || x == N - 1) ? 1.f : 0.5f;
    float hy = (y == 0 || y == N - 1) ? 1.f : 0.5f;
    f4 rxp = ld4(base + (long)xp * n2 + (long)y * N + z);
    f4 rxm = ld4(base + (long)xm * n2 + (long)y * N + z);
    f4 ryp = ld4(base + (long)x * n2 + (long)yp * N + z);
    f4 rym = ld4(base + (long)x * n2 + (long)ym * N + z);

    f4 outv;
#pragma unroll
    for (int j = 0; j < 4; ++j) {
        float c = cur[j];
        float zmv = (j == 0) ? prev[3] : cur[(j == 0) ? 0 : j - 1];
        float zpv = (j == 3) ? next[0] : cur[(j == 3) ? 3 : j + 1];
        int gz = z + j;
        float dz = (gz == 0) ? (zpv - c) : ((gz == N - 1) ? (c - zmv) : 0.5f * (zpv - zmv));
        float dx = hx * (rxp[j] - rxm[j]);
        float dy = hy * (ryp[j] - rym[j]);
        outv[j] = sqrtf(dx * dx + dy * dy + dz * dz);
    }
    *(f4*)(g + (long)b * n3 + (long)x * n2 + (long)y * N + z) = outv;
}

__global__ __launch_bounds__(TPB)
void gradmag_all(const float* __restrict__ I0, const float* __restrict__ is1,
                 const float* __restrict__ is2, float* __restrict__ g0,
                 float* __restrict__ g1, float* __restrict__ g2) {
    int blk = blockIdx.x;
    if (blk < EB0)            gradmag_one<160>(I0,  g0, (long)blk * TPB + threadIdx.x);
    else if (blk < EB0 + EB1) gradmag_one<80> (is1, g1, (long)(blk - EB0) * TPB + threadIdx.x);
    else                      gradmag_one<40> (is2, g2, (long)(blk - EB0 - EB1) * TPB + threadIdx.x);
}

// -------- fused blur x+y, 4 outputs per thread along y --------
template <int N>
__device__ __forceinline__ void blur_one(const float* __restrict__ in,
                                         float* __restrict__ out, long idx) {
    constexpr int NZ4 = N / 4, NY4 = N / 4;
    constexpr long n2 = (long)N * N, n3 = n2 * N;
    int z4 = (int)(idx % NZ4); long r = idx / NZ4;
    int y4 = (int)(r % NY4); r /= NY4;
    int x = (int)(r % N); int b = (int)(r / N);
    int y0 = y4 * 4, z = z4 * 4;

    const float K[5] = {K0, K1, K2, K1, K0};
    const float* base = in + (long)b * n3 + z;

    f4 cs[8];
#pragma unroll
    for (int jj = 0; jj < 8; ++jj) cs[jj] = (f4){0.f, 0.f, 0.f, 0.f};

#pragma unroll
    for (int i = 0; i < 5; ++i) {
        int qx = rref(x + i - 2, N);
        const float* px = base + (long)qx * n2;
#pragma unroll
        for (int jj = 0; jj < 8; ++jj) {
            int qy = rref(y0 - 2 + jj, N);
            cs[jj] += K[i] * ld4(px + (long)qy * N);
        }
    }
    float* ob = out + (long)b * n3 + (long)x * n2 + z;
#pragma unroll
    for (int k = 0; k < 4; ++k) {
        f4 o = K0 * cs[k] + K1 * cs[k + 1] + K2 * cs[k + 2] + K1 * cs[k + 3] + K0 * cs[k + 4];
        *(f4*)(ob + (long)(y0 + k) * N) = o;
    }
}

__global__ __launch_bounds__(TPB)
void blur_all(const float* __restrict__ g0, const float* __restrict__ g1,
              const float* __restrict__ g2, float* __restrict__ t0,
              float* __restrict__ t1, float* __restrict__ t2) {
    int blk = blockIdx.x;
    if (blk < BB0)            blur_one<160>(g0, t0, (long)blk * TPB + threadIdx.x);
    else if (blk < BB0 + BB1) blur_one<80> (g1, t1, (long)(blk - BB0) * TPB + threadIdx.x);
    else {
        long idx = (long)(blk - BB0 - BB1) * TPB + threadIdx.x;
        if (idx < 8000) blur_one<40>(g2, t2, idx);
    }
}

// -------- energy half-compute: one f4 at absolute z, given z-window regs --------
template <int N>
__device__ __forceinline__ float energy_quad(const float* __restrict__ base, long rowoff,
                                             long oxp, long oxm, long oyp, long oym,
                                             float hx, float hy,
                                             const f4* CC, const f4* CP, const f4* CN,
                                             const f4& gp, const f4& gc, const f4& gn, int z) {
    constexpr long n3 = (long)N * N * N;
    f4 RXP[3], RXM[3], RYP[3], RYM[3];
#pragma unroll
    for (int c = 0; c < 3; ++c) {
        const float* rc = base + (long)c * n3 + rowoff;
        RXP[c] = ld4(rc + oxp);
        RXM[c] = ld4(rc + oxm);
        RYP[c] = ld4(rc + oyp);
        RYM[c] = ld4(rc + oym);
    }
    float gw[12];
#pragma unroll
    for (int i = 0; i < 4; ++i) { gw[i] = gp[i]; gw[4 + i] = gc[i]; gw[8 + i] = gn[i]; }

    float lsum = 0.f;
#pragma unroll
    for (int j = 0; j < 4; ++j) {
        int gz = z + j;
        float dX[3], dY[3], dZ[3];
#pragma unroll
        for (int c = 0; c < 3; ++c) {
            float cc = CC[c][j];
            float zmv = (j == 0) ? CP[c][3] : CC[c][(j == 0) ? 0 : j - 1];
            float zpv = (j == 3) ? CN[c][0] : CC[c][(j == 3) ? 3 : j + 1];
            dZ[c] = (gz == 0) ? (zpv - cc)
                              : ((gz == N - 1) ? (cc - zmv) : 0.5f * (zpv - zmv));
            dX[c] = hx * (RXP[c][j] - RXM[c][j]);
            dY[c] = hy * (RYP[c][j] - RYM[c][j]);
        }
        float igv = K0 * gw[2 + j] + K1 * gw[3 + j] + K2 * gw[4 + j]
                  + K1 * gw[5 + j] + K0 * gw[6 + j];
        float lam = fminf(fmaxf(1.0f + 2.0f * igv, 0.1f), 10.0f);
        float mu  = fminf(fmaxf(0.5f + 1.0f * igv, 0.1f), 10.0f);
        float wt  = 1.0f + 5.0f * igv;

        float Exx = dX[0], Eyy = dY[1], Ezz = dZ[2];
        float Exy = 0.5f * (dY[0] + dX[1]);
        float Exz = 0.5f * (dZ[0] + dX[2]);
        float Eyz = 0.5f * (dZ[1] + dY[2]);
        float tr = Exx + Eyy + Ezz;
        float e = 0.5f * lam * tr * tr +
                  mu * (Exx * Exx + Eyy * Eyy + Ezz * Ezz +
                        2.0f * (Exy * Exy + Exz * Exz + Eyz * Eyz));
        lsum += wt * e;
    }
    return lsum;
}

// -------- Lame energy, z8 pair per thread (shared z-window) --------
template <int N>
__device__ __forceinline__ float energy_pair(const float* __restrict__ def,
                                             const float* __restrict__ igxy, long idx) {
    constexpr int NZ8 = N / 8;
    constexpr long n2 = (long)N * N, n3 = n2 * N;
    int z8 = (int)(idx % NZ8); long r = idx / NZ8;
    int y = (int)(r % N); r /= N;
    int x = (int)(r % N); int b = (int)(r / N);
    int z = z8 * 8;

    int xm = max(x - 1, 0), xp = min(x + 1, N - 1);
    int ym = max(y - 1, 0), yp = min(y + 1, N - 1);
    float hx = (x == 0 || x == N - 1) ? 1.f : 0.5f;
    float hy = (y == 0 || y == N - 1) ? 1.f : 0.5f;

    const float* base = def + (long)b * 3 * n3;
    long sp = (long)x * n2 + (long)y * N + z;
    long oxp = (long)(xp - x) * n2, oxm = (long)(xm - x) * n2;
    long oyp = (long)(yp - y) * N,  oym = (long)(ym - y) * N;

    // shared z-window: CC0 (z), CC1 (z+4), CP0 (z-4), CN1 (z+8)
    f4 CC0[3], CC1[3], CP0[3], CN1[3];
#pragma unroll
    for (int c = 0; c < 3; ++c) {
        const float* rc = base + (long)c * n3 + sp;
        CC0[c] = ld4(rc);
        CC1[c] = ld4(rc + 4);
        CP0[c] = (z > 0) ? ld4(rc - 4) : CC0[c];
        CN1[c] = (z + 8 < N) ? ld4(rc + 8) : CC1[c];
    }

    // ig z-window (reflect boundary)
    const float* growc = igxy + (long)b * n3 + (long)x * n2 + (long)y * N;
    f4 gc0 = ld4(growc + z), gc1 = ld4(growc + z + 4);
    f4 gp0, gn1;
    if (z >= 4) gp0 = ld4(growc + z - 4);
    else { gp0[0] = growc[4]; gp0[1] = growc[3]; gp0[2] = growc[2]; gp0[3] = growc[1]; }
    if (z + 12 <= N) gn1 = ld4(growc + z + 8);
    else { gn1[0] = growc[N - 2]; gn1[1] = growc[N - 3]; gn1[2] = growc[N - 4]; gn1[3] = growc[N - 5]; }

    float lsum = energy_quad<N>(base, sp, oxp, oxm, oyp, oym, hx, hy,
                                CC0, CP0, CC1, gp0, gc0, gc1, z);
    lsum += energy_quad<N>(base, sp + 4, oxp, oxm, oyp, oym, hx, hy,
                           CC1, CC0, CN1, gc0, gc1, gn1, z + 4);
    return lsum;
}

__global__ __launch_bounds__(TPB)
void energy_all(const float* __restrict__ D, const float* __restrict__ ds1,
                const float* __restrict__ ds2, const float* __restrict__ t0,
                const float* __restrict__ t1, const float* __restrict__ t2,
                float* __restrict__ partial) {
    int blk = blockIdx.x;
    float lsum = 0.f;
    if (blk < PB0)            lsum = energy_pair<160>(D,   t0, (long)blk * TPB + threadIdx.x);
    else if (blk < PB0 + PB1) lsum = energy_pair<80> (ds1, t1, (long)(blk - PB0) * TPB + threadIdx.x);
    else {
        long idx = (long)(blk - PB0 - PB1) * TPB + threadIdx.x;
        if (idx < 16000) lsum = energy_pair<40>(ds2, t2, idx);
    }

    __shared__ float sm[TPB];
    sm[threadIdx.x] = lsum;
    __syncthreads();
    for (int s = TPB / 2; s > 0; s >>= 1) {
        if (threadIdx.x < s) sm[threadIdx.x] += sm[threadIdx.x + s];
        __syncthreads();
    }
    if (threadIdx.x == 0) partial[blk] = sm[0];
}

// -------- combine scale partials + Jacobian penalty -> out[0] --------
__global__ __launch_bounds__(TPB)
void finalize_kernel(const float* __restrict__ partial,
                     const float* __restrict__ def, float* __restrict__ out) {
    __shared__ float sm[TPB];
    const float wts[3] = {1.0f, 0.5f, 0.25f};
    const float invcnt[3] = {1.0f / (2.0f * 160 * 160 * 160),
                             1.0f / (2.0f * 80 * 80 * 80),
                             1.0f / (2.0f * 40 * 40 * 40)};
    const int offs[3] = {0, PB0, PB0 + PB1};
    const int cnts[3] = {PB0, PB1, PB2};
    float acc = 0.f;
    for (int s = 0; s < 3; ++s) {
        float local = 0.f;
        for (int i = threadIdx.x; i < cnts[s]; i += TPB) local += partial[offs[s] + i];
        acc += wts[s] * invcnt[s] * local;
    }
    sm[threadIdx.x] = acc;
    __syncthreads();
    for (int s = TPB / 2; s > 0; s >>= 1) {
        if (threadIdx.x < s) sm[threadIdx.x] += sm[threadIdx.x + s];
        __syncthreads();
    }
    if (threadIdx.x == 0) {
        float jac = 0.f;
        const int n = 160;
        long n3 = (long)n * n * n;
        long ctr = ((long)80 * n + 80) * n + 80;
        for (int b = 0; b < 2; ++b) {
            const float* p = def + (long)b * 3 * n3;
            float J[3][3];
            for (int c = 0; c < 3; ++c) {
                const float* q = p + (long)c * n3 + ctr;
                J[c][0] = 0.5f * (q[(long)n * n] - q[-(long)n * n]);
                J[c][1] = 0.5f * (q[n] - q[-n]);
                J[c][2] = 0.5f * (q[1] - q[-1]);
            }
            float det = J[0][0] * (J[1][1] * J[2][2] - J[1][2] * J[2][1])
                      - J[0][1] * (J[1][0] * J[2][2] - J[1][2] * J[2][0])
                      + J[0][2] * (J[1][0] * J[2][1] - J[1][1] * J[2][0]);
            jac += fmaxf(-det, 0.f);
        }
        jac *= 0.5f; // mean over B=2
        out[0] = sm[0] + 0.1f * jac;
    }
}

extern "C" void kernel_launch(void* const* d_in, const int* in_sizes, int n_in,
                              void* d_out, int out_size, void* d_ws, size_t ws_size,
                              hipStream_t stream) {
    const float* D = (const float*)d_in[0];  // (2,3,160,160,160)
    const float* I = (const float*)d_in[1];  // (2,1,160,160,160)
    float* out = (float*)d_out;
    float* ws = (float*)d_ws;

    const int B = 2;
    const long S0 = (long)B * 160 * 160 * 160;
    const long S1 = (long)B * 80 * 80 * 80;
    const long S2 = (long)B * 40 * 40 * 40;

    // disjoint workspace layout
    float* partials = ws;                 // 9216 (uses [0, 4563))
    float* ds1 = partials + 9216;         // 3*S1
    float* is1 = ds1 + 3 * S1;            // S1
    float* g1  = is1 + S1;                // S1
    float* t1  = g1 + S1;                 // S1
    float* ds2 = t1 + S1;                 // 3*S2
    float* is2 = ds2 + 3 * S2;            // S2
    float* g2  = is2 + S2;                // S2
    float* t2  = g2 + S2;                 // S2
    float* g0  = t2 + S2;                 // S0
    float* t0  = g0 + S0;                 // S0

    // 1) all four resizes (M=80 f4-vectorized, M=40 scalar)
    resize_all_kernel<<<RBLK, TPB, 0, stream>>>(D, I, ds1, ds2, is1, is2);
    // 2) gradmag, all scales (per-f4)
    gradmag_all<<<EB0 + EB1 + EB2, TPB, 0, stream>>>(I, is1, is2, g0, g1, g2);
    // 3) blur x+y, all scales (y4)
    blur_all<<<BB0 + BB1 + BB2, TPB, 0, stream>>>(g0, g1, g2, t0, t1, t2);
    // 4) energy (+ in-register z-blur), z8 pair per thread
    energy_all<<<PB0 + PB1 + PB2, TPB, 0, stream>>>(D, ds1, ds2, t0, t1, t2, partials);
    // 5) finalize
    finalize_kernel<<<1, TPB, 0, stream>>>(partials, D, out);
}